// Round 4
// baseline (556.615 us; speedup 1.0000x reference)
//
#include <hip/hip_runtime.h>

#define B_ 8
#define C_ 256
#define N_ 4096
#define G_ 32

typedef __bf16 bf16;
typedef __bf16 bf16x8 __attribute__((ext_vector_type(8)));
typedef float f32x4 __attribute__((ext_vector_type(4)));
typedef unsigned int u32;

__device__ __forceinline__ f32x4 mfma16(bf16x8 a, bf16x8 b, f32x4 c) {
    return __builtin_amdgcn_mfma_f32_16x16x32_bf16(a, b, c, 0, 0, 0);
}

typedef __attribute__((address_space(1))) const void* gas_t;
typedef __attribute__((address_space(3))) void* las_t;
__device__ __forceinline__ void gl2lds16(const void* g, void* l) {
    __builtin_amdgcn_global_load_lds((gas_t)g, (las_t)l, 16, 0, 0);
}

// Swizzled LDS readers. K: 32 rows x 256 cols, chunk(16B) swizzle ch^(r&7).
// V^T: 256 rows x 32 cols, chunk swizzle ch^((r>>2)&3). Both give <=2-way
// conflicts (free) on MFMA fragment reads AND flat chunk order for DMA staging.
__device__ __forceinline__ bf16x8 ldsK(const bf16* base, int r, int ch) {
    return *(const bf16x8*)(base + (((r << 5) + (ch ^ (r & 7))) << 3));
}
__device__ __forceinline__ bf16x8 ldsV(const bf16* base, int r, int ch) {
    return *(const bf16x8*)(base + (((r << 2) + (ch ^ ((r >> 2) & 3))) << 3));
}

// ---------------------------------------------------------------------------
// Kernel 1: GroupNorm statistics. One block per (batch, group).
// ---------------------------------------------------------------------------
__global__ __launch_bounds__(256) void gn_stats(const float* __restrict__ x,
                                                float* __restrict__ gstats) {
    int blk = blockIdx.x;  // b*32 + g
    int b = blk >> 5, g = blk & 31;
    int tid = threadIdx.x;
    int c = g * 8 + (tid >> 5);
    const float* row = x + ((size_t)(b * C_ + c)) * N_;
    float s = 0.f, s2 = 0.f;
    for (int n = (tid & 31) * 4; n < N_; n += 128) {
        float4 v = *(const float4*)(row + n);
        s += v.x + v.y + v.z + v.w;
        s2 += v.x * v.x + v.y * v.y + v.z * v.z + v.w * v.w;
    }
    for (int off = 32; off; off >>= 1) {
        s += __shfl_xor(s, off);
        s2 += __shfl_xor(s2, off);
    }
    __shared__ float red[8];
    int wid = tid >> 6;
    if ((tid & 63) == 0) { red[wid] = s; red[4 + wid] = s2; }
    __syncthreads();
    if (tid == 0) {
        float S = red[0] + red[1] + red[2] + red[3];
        float S2 = red[4] + red[5] + red[6] + red[7];
        float mean = S * (1.f / 32768.f);
        float var = S2 * (1.f / 32768.f) - mean * mean;
        gstats[blk * 2] = mean;
        gstats[blk * 2 + 1] = rsqrtf(var + 1e-6f);
    }
}

// ---------------------------------------------------------------------------
// Kernel 2: apply GroupNorm + transpose [b][c][n] fp32 -> [b*n][c] bf16.
// ---------------------------------------------------------------------------
__global__ __launch_bounds__(256) void gn_apply(const float* __restrict__ x,
                                                const float* __restrict__ gsc,
                                                const float* __restrict__ gbi,
                                                const float* __restrict__ gstats,
                                                bf16* __restrict__ hn) {
    __shared__ float tile[32][33];
    int b = blockIdx.z, c0 = blockIdx.y * 32, n0 = blockIdx.x * 32;
    int tx = threadIdx.x & 31, ty = threadIdx.x >> 5;
    for (int i = 0; i < 4; i++) {
        int cl = ty + i * 8;
        int c = c0 + cl;
        int g = c >> 3;
        float mean = gstats[(b * G_ + g) * 2];
        float rstd = gstats[(b * G_ + g) * 2 + 1];
        float sc = gsc[c] * rstd;
        float bs = gbi[c] - mean * sc;
        float v = x[((size_t)(b * C_ + c)) * N_ + n0 + tx];
        tile[cl][tx] = v * sc + bs;
    }
    __syncthreads();
    for (int i = 0; i < 4; i++) {
        int nl = ty + i * 8;
        hn[((size_t)(b * N_ + n0 + nl)) * C_ + c0 + tx] = (bf16)tile[tx][nl];
    }
}

// ---------------------------------------------------------------------------
// Kernel 3: convert the four 256x256 fp32 weight matrices to bf16 once.
// ---------------------------------------------------------------------------
__global__ __launch_bounds__(256) void cvt_w(const float* __restrict__ wq,
                                             const float* __restrict__ wk,
                                             const float* __restrict__ wv,
                                             const float* __restrict__ wp,
                                             bf16* __restrict__ dst) {
    int i = blockIdx.x * 256 + threadIdx.x;
    dst[i] = (bf16)wq[i];
    dst[65536 + i] = (bf16)wk[i];
    dst[131072 + i] = (bf16)wv[i];
    dst[196608 + i] = (bf16)wp[i];
}

// ---------------------------------------------------------------------------
// Kernel 4: merged Q+K NT GEMM, token-major outputs. A-tile staged once.
// ---------------------------------------------------------------------------
__global__ __launch_bounds__(256) void gemm_qk(const bf16* __restrict__ A,
                                               const bf16* __restrict__ Wq,
                                               const bf16* __restrict__ Wk,
                                               const float* __restrict__ bq,
                                               const float* __restrict__ bk,
                                               bf16* __restrict__ qout,
                                               bf16* __restrict__ kout) {
    __shared__ __align__(16) bf16 As[64][32];
    __shared__ __align__(16) bf16 Wqs[64][32];
    __shared__ __align__(16) bf16 Wks[64][32];
    int m0 = blockIdx.x * 64, n0 = blockIdx.y * 64;
    int tid = threadIdx.x;
    int wv = tid >> 6, lane = tid & 63, lr = lane & 15, lq = lane >> 4;
    int wm = (wv & 1) * 32, wn = (wv >> 1) * 32;
    int sr = tid >> 2, sk = (tid & 3) * 8;
    f32x4 qacc[2][2] = {}, kacc[2][2] = {};
    for (int kk = 0; kk < C_; kk += 32) {
        __syncthreads();
        *(bf16x8*)&As[sr][sk] = *(const bf16x8*)&A[(size_t)(m0 + sr) * C_ + kk + sk];
        *(bf16x8*)&Wqs[sr][sk] = *(const bf16x8*)&Wq[(size_t)(n0 + sr) * C_ + kk + sk];
        *(bf16x8*)&Wks[sr][sk] = *(const bf16x8*)&Wk[(size_t)(n0 + sr) * C_ + kk + sk];
        __syncthreads();
        bf16x8 a0 = *(const bf16x8*)&As[wm + lr][lq * 8];
        bf16x8 a1 = *(const bf16x8*)&As[wm + 16 + lr][lq * 8];
        bf16x8 q0 = *(const bf16x8*)&Wqs[wn + lr][lq * 8];
        bf16x8 q1 = *(const bf16x8*)&Wqs[wn + 16 + lr][lq * 8];
        bf16x8 k0 = *(const bf16x8*)&Wks[wn + lr][lq * 8];
        bf16x8 k1 = *(const bf16x8*)&Wks[wn + 16 + lr][lq * 8];
        qacc[0][0] = mfma16(a0, q0, qacc[0][0]);
        qacc[0][1] = mfma16(a0, q1, qacc[0][1]);
        qacc[1][0] = mfma16(a1, q0, qacc[1][0]);
        qacc[1][1] = mfma16(a1, q1, qacc[1][1]);
        kacc[0][0] = mfma16(a0, k0, kacc[0][0]);
        kacc[0][1] = mfma16(a0, k1, kacc[0][1]);
        kacc[1][0] = mfma16(a1, k0, kacc[1][0]);
        kacc[1][1] = mfma16(a1, k1, kacc[1][1]);
    }
    for (int i = 0; i < 2; i++)
        for (int j = 0; j < 2; j++) {
            int col = n0 + wn + j * 16 + lr;
            float bvq = bq[col], bvk = bk[col];
            for (int r = 0; r < 4; r++) {
                int row = m0 + wm + i * 16 + lq * 4 + r;
                qout[(size_t)row * C_ + col] = (bf16)(qacc[i][j][r] + bvq);
                kout[(size_t)row * C_ + col] = (bf16)(kacc[i][j][r] + bvk);
            }
        }
}

// ---------------------------------------------------------------------------
// Kernel 5: NT GEMM, channel-major output (V^T).
// ---------------------------------------------------------------------------
__global__ __launch_bounds__(256) void gemm_nt_ch(const bf16* __restrict__ W,
                                                  const bf16* __restrict__ A,
                                                  const float* __restrict__ bias,
                                                  bf16* __restrict__ outT) {
    __shared__ __align__(16) bf16 Ws[64][32];
    __shared__ __align__(16) bf16 As[64][32];
    int m0 = blockIdx.x * 64;  // o
    int n0 = blockIdx.y * 64;  // token
    int tid = threadIdx.x;
    int wv = tid >> 6, lane = tid & 63, lr = lane & 15, lq = lane >> 4;
    int wm = (wv & 1) * 32, wn = (wv >> 1) * 32;
    int sr = tid >> 2, sk = (tid & 3) * 8;
    f32x4 acc[2][2] = {};
    for (int kk = 0; kk < C_; kk += 32) {
        __syncthreads();
        *(bf16x8*)&Ws[sr][sk] = *(const bf16x8*)&W[(size_t)(m0 + sr) * C_ + kk + sk];
        *(bf16x8*)&As[sr][sk] = *(const bf16x8*)&A[(size_t)(n0 + sr) * C_ + kk + sk];
        __syncthreads();
        bf16x8 a0 = *(const bf16x8*)&Ws[wm + lr][lq * 8];
        bf16x8 a1 = *(const bf16x8*)&Ws[wm + 16 + lr][lq * 8];
        bf16x8 b0 = *(const bf16x8*)&As[wn + lr][lq * 8];
        bf16x8 b1 = *(const bf16x8*)&As[wn + 16 + lr][lq * 8];
        acc[0][0] = mfma16(a0, b0, acc[0][0]);
        acc[0][1] = mfma16(a0, b1, acc[0][1]);
        acc[1][0] = mfma16(a1, b0, acc[1][0]);
        acc[1][1] = mfma16(a1, b1, acc[1][1]);
    }
    for (int i = 0; i < 2; i++)
        for (int j = 0; j < 2; j++) {
            int T = n0 + wn + j * 16 + lr;
            int b = T >> 12, n = T & (N_ - 1);
            for (int r = 0; r < 4; r++) {
                int o = m0 + wm + i * 16 + lq * 4 + r;
                outT[((size_t)(b * C_ + o)) * N_ + n] = (bf16)(acc[i][j][r] + bias[o]);
            }
        }
}

// ---------------------------------------------------------------------------
// Kernel 6: flash attention, intra-block split-K.
//   512 threads = 8 waves; 128 queries/block. Waves 0-3 process keys
//   [0,2048), waves 4-7 keys [2048,4096) — each half has its own
//   double-buffered K/V tiles. grid=256 -> 1 block/CU -> 8 waves/CU
//   (2/SIMD), 2x the TLP of R3. Fixed-max softmax => halves combine
//   linearly at the end through (repurposed) LDS. No extra HBM traffic.
// ---------------------------------------------------------------------------
__global__ __launch_bounds__(512, 2) void attn(const bf16* __restrict__ q,
                                               const bf16* __restrict__ k,
                                               const bf16* __restrict__ vT,
                                               bf16* __restrict__ hm) {
    __shared__ __align__(16) char smem[151552];
    bf16* KsBase = (bf16*)smem;                  // [h][buf][32*256] = 64 KB
    bf16* VtBase = (bf16*)(smem + 65536);        // [h][buf][256*32] = 64 KB
    bf16* PsBase = (bf16*)(smem + 131072);       // [w4][32][40]    = 20 KB

    int b = blockIdx.y, q0 = blockIdx.x * 128;
    int tid = threadIdx.x;
    int w4 = tid >> 6;       // wave 0..7
    int h = w4 >> 2;         // key half
    int wq = w4 & 3;         // query subtile
    int lane = tid & 63, lr = lane & 15, lq = lane >> 4;

    const bf16* kglob = k + ((size_t)(b * N_) + h * 2048) * C_;
    const bf16* vglob = vT + (size_t)b * C_ * N_ + h * 2048;

    // Per-lane staging offsets (iteration-invariant); 4+4 chunks per wave.
    u32 offK[4], offV[4];
#pragma unroll
    for (int j = 0; j < 4; j++) {
        int p = ((wq * 4 + j) << 6) + lane;  // 0..1023 16B-chunk index
        int rK = p >> 5, cK = (p & 31) ^ (rK & 7);
        offK[j] = rK * C_ + cK * 8;
        int rV = p >> 2, cV = (p & 3) ^ ((rV >> 2) & 3);
        offV[j] = rV * N_ + cV * 8;
    }

    // Q fragments: 32 queries per wave.
    bf16x8 qf[2][8];
#pragma unroll
    for (int t = 0; t < 2; t++) {
        const bf16* qrow = q + ((size_t)(b * N_ + q0 + wq * 32 + t * 16 + lr)) * C_;
#pragma unroll
        for (int kc = 0; kc < 8; kc++) qf[t][kc] = *(const bf16x8*)&qrow[kc * 32 + lq * 8];
    }

    f32x4 oacc[2][16] = {};
    float li[2][4] = {};  // per-lane partial row sums
    bf16* Pw = PsBase + w4 * 1280;

    // Prologue: stage tile 0 of this wave's half into buffer 0.
#pragma unroll
    for (int j = 0; j < 4; j++) {
        gl2lds16(kglob + offK[j], KsBase + (h * 2) * 8192 + ((wq * 4 + j) << 9));
        gl2lds16(vglob + offV[j], VtBase + (h * 2) * 8192 + ((wq * 4 + j) << 9));
    }

    for (int mt = 0; mt < 64; mt++) {
        int cur = mt & 1;
        __syncthreads();  // drains buf[cur] DMA; everyone done reading buf[cur^1]

        if (mt < 63) {  // async prefetch of next tile into the idle buffer
            const bf16* kit = kglob + (size_t)(mt + 1) * 32 * C_;
            const bf16* vit = vglob + (mt + 1) * 32;
#pragma unroll
            for (int j = 0; j < 4; j++) {
                gl2lds16(kit + offK[j], KsBase + (h * 2 + (cur ^ 1)) * 8192 + ((wq * 4 + j) << 9));
                gl2lds16(vit + offV[j], VtBase + (h * 2 + (cur ^ 1)) * 8192 + ((wq * 4 + j) << 9));
            }
        }

        const bf16* Kb = KsBase + (h * 2 + cur) * 8192;
        const bf16* Vb = VtBase + (h * 2 + cur) * 8192;

        // --- S = Q K^T: 32 queries x 32 keys (2x2 MFMA tiles) ---
        f32x4 st[2][2] = {};
#pragma unroll
        for (int kc = 0; kc < 8; kc++) {
            bf16x8 kb0 = ldsK(Kb, lr, kc * 4 + lq);
            bf16x8 kb1 = ldsK(Kb, 16 + lr, kc * 4 + lq);
            st[0][0] = mfma16(qf[0][kc], kb0, st[0][0]);
            st[1][0] = mfma16(qf[1][kc], kb0, st[1][0]);
            st[0][1] = mfma16(qf[0][kc], kb1, st[0][1]);
            st[1][1] = mfma16(qf[1][kc], kb1, st[1][1]);
        }

        // --- fixed-max softmax numerator: p = exp(s/16) ---
#pragma unroll
        for (int t = 0; t < 2; t++)
#pragma unroll
            for (int r = 0; r < 4; r++) {
                float p0 = __expf(st[t][0][r] * 0.0625f);
                float p1 = __expf(st[t][1][r] * 0.0625f);
                li[t][r] += p0 + p1;
                Pw[(t * 16 + lq * 4 + r) * 40 + lr] = (bf16)p0;
                Pw[(t * 16 + lq * 4 + r) * 40 + 16 + lr] = (bf16)p1;
            }

        // --- PV: P (32x32) x V (32x256) ---
        bf16x8 pf0 = *(const bf16x8*)&Pw[lr * 40 + lq * 8];
        bf16x8 pf1 = *(const bf16x8*)&Pw[(16 + lr) * 40 + lq * 8];
#pragma unroll
        for (int ct = 0; ct < 16; ct++) {
            bf16x8 vf = ldsV(Vb, ct * 16 + lr, lq);
            oacc[0][ct] = mfma16(pf0, vf, oacc[0][ct]);
            oacc[1][ct] = mfma16(pf1, vf, oacc[1][ct]);
        }
    }

    // Reduce per-lane l partials across the 16 lr-lanes (once).
    float lsum[2][4];
#pragma unroll
    for (int t = 0; t < 2; t++)
#pragma unroll
        for (int r = 0; r < 4; r++) {
            float s = li[t][r];
            s += __shfl_xor(s, 1);
            s += __shfl_xor(s, 2);
            s += __shfl_xor(s, 4);
            s += __shfl_xor(s, 8);
            lsum[t][r] = s;
        }

    // --- combine the two key-halves through LDS (KsBase repurposed) ---
    __syncthreads();  // all waves done with K/V/P tiles
    if (h == 1) {
        bf16* O1 = KsBase + wq * 8192;  // [32 rows][256 cols], ct-chunk swizzled
        float* L1 = (float*)PsBase + wq * 32;
#pragma unroll
        for (int t = 0; t < 2; t++)
#pragma unroll
            for (int ct = 0; ct < 16; ct++) {
                int row0 = t * 16 + lq * 4;
#pragma unroll
                for (int r = 0; r < 4; r++) {
                    int row = row0 + r;
                    O1[row * 256 + ((ct ^ (row & 15)) << 4) + lr] = (bf16)oacc[t][ct][r];
                }
            }
        if (lr == 0) {
#pragma unroll
            for (int t = 0; t < 2; t++)
#pragma unroll
                for (int r = 0; r < 4; r++) L1[t * 16 + lq * 4 + r] = lsum[t][r];
        }
    }
    __syncthreads();
    if (h == 0) {
        const bf16* O1 = KsBase + wq * 8192;
        const float* L1 = (const float*)PsBase + wq * 32;
        float inv[2][4];
#pragma unroll
        for (int t = 0; t < 2; t++)
#pragma unroll
            for (int r = 0; r < 4; r++)
                inv[t][r] = 1.f / (lsum[t][r] + L1[t * 16 + lq * 4 + r]);
#pragma unroll
        for (int t = 0; t < 2; t++)
#pragma unroll
            for (int ct = 0; ct < 16; ct++) {
#pragma unroll
                for (int r = 0; r < 4; r++) {
                    int row = t * 16 + lq * 4 + r;
                    float o = oacc[t][ct][r] + (float)O1[row * 256 + ((ct ^ (row & 15)) << 4) + lr];
                    hm[((size_t)(b * N_ + q0 + wq * 32 + row)) * C_ + ct * 16 + lr] =
                        (bf16)(o * inv[t][r]);
                }
            }
    }
}

// ---------------------------------------------------------------------------
// Kernel 7: proj + residual.
// ---------------------------------------------------------------------------
__global__ __launch_bounds__(256) void proj_res(const bf16* __restrict__ W,
                                                const bf16* __restrict__ A,
                                                const float* __restrict__ bias,
                                                const float* __restrict__ x,
                                                float* __restrict__ out) {
    __shared__ __align__(16) bf16 Ws[64][32];
    __shared__ __align__(16) bf16 As[64][32];
    int m0 = blockIdx.x * 64;  // o
    int n0 = blockIdx.y * 64;  // token
    int tid = threadIdx.x;
    int wv = tid >> 6, lane = tid & 63, lr = lane & 15, lq = lane >> 4;
    int wm = (wv & 1) * 32, wn = (wv >> 1) * 32;
    int sr = tid >> 2, sk = (tid & 3) * 8;
    f32x4 acc[2][2] = {};
    for (int kk = 0; kk < C_; kk += 32) {
        __syncthreads();
        *(bf16x8*)&Ws[sr][sk] = *(const bf16x8*)&W[(size_t)(m0 + sr) * C_ + kk + sk];
        *(bf16x8*)&As[sr][sk] = *(const bf16x8*)&A[(size_t)(n0 + sr) * C_ + kk + sk];
        __syncthreads();
        bf16x8 a0 = *(const bf16x8*)&Ws[wm + lr][lq * 8];
        bf16x8 a1 = *(const bf16x8*)&Ws[wm + 16 + lr][lq * 8];
        bf16x8 b0 = *(const bf16x8*)&As[wn + lr][lq * 8];
        bf16x8 b1 = *(const bf16x8*)&As[wn + 16 + lr][lq * 8];
        acc[0][0] = mfma16(a0, b0, acc[0][0]);
        acc[0][1] = mfma16(a0, b1, acc[0][1]);
        acc[1][0] = mfma16(a1, b0, acc[1][0]);
        acc[1][1] = mfma16(a1, b1, acc[1][1]);
    }
    for (int i = 0; i < 2; i++)
        for (int j = 0; j < 2; j++) {
            int T = n0 + wn + j * 16 + lr;
            int b = T >> 12, n = T & (N_ - 1);
            for (int r = 0; r < 4; r++) {
                int o = m0 + wm + i * 16 + lq * 4 + r;
                size_t idx = ((size_t)(b * C_ + o)) * N_ + n;
                out[idx] = x[idx] + acc[i][j][r] + bias[o];
            }
        }
}

// ---------------------------------------------------------------------------
extern "C" void kernel_launch(void* const* d_in, const int* in_sizes, int n_in,
                              void* d_out, int out_size, void* d_ws, size_t ws_size,
                              hipStream_t stream) {
    const float* x = (const float*)d_in[0];
    const float* gsc = (const float*)d_in[1];
    const float* gbi = (const float*)d_in[2];
    const float* wq = (const float*)d_in[3];
    const float* bq = (const float*)d_in[4];
    const float* wk = (const float*)d_in[5];
    const float* bk = (const float*)d_in[6];
    const float* wv = (const float*)d_in[7];
    const float* bv = (const float*)d_in[8];
    const float* wp = (const float*)d_in[9];
    const float* bp = (const float*)d_in[10];
    float* out = (float*)d_out;

    const size_t SZ = (size_t)B_ * N_ * C_;  // 8388608 elements
    char* ws = (char*)d_ws;
    float* gstats = (float*)ws;              // 512 floats
    bf16* wb = (bf16*)(ws + 4096);           // 4 x 65536 bf16
    bf16* hn = (bf16*)(ws + 4096 + 524288);  // [B*N][C]
    bf16* qb = hn + SZ;
    bf16* kb = qb + SZ;
    bf16* vT = kb + SZ;  // [B][C][N]
    bf16* hm = hn;       // alias: hn dead after QKV GEMMs

    cvt_w<<<256, 256, 0, stream>>>(wq, wk, wv, wp, wb);
    gn_stats<<<B_ * G_, 256, 0, stream>>>(x, gstats);
    gn_apply<<<dim3(N_ / 32, C_ / 32, B_), 256, 0, stream>>>(x, gsc, gbi, gstats, hn);
    gemm_qk<<<dim3(B_ * N_ / 64, C_ / 64), 256, 0, stream>>>(hn, wb, wb + 65536, bq, bk, qb, kb);
    gemm_nt_ch<<<dim3(C_ / 64, B_ * N_ / 64), 256, 0, stream>>>(wb + 131072, hn, bv, vT);
    attn<<<dim3(N_ / 128, B_), 512, 0, stream>>>(qb, kb, vT, hm);
    proj_res<<<dim3(C_ / 64, B_ * N_ / 64), 256, 0, stream>>>(wb + 196608, hm, bp, x, out);
}

// Round 6
// 454.778 us; speedup vs baseline: 1.2239x; 1.2239x over previous
//
#include <hip/hip_runtime.h>

#define B_ 8
#define C_ 256
#define N_ 4096
#define G_ 32

typedef __bf16 bf16;
typedef __bf16 bf16x8 __attribute__((ext_vector_type(8)));
typedef float f32x4 __attribute__((ext_vector_type(4)));
typedef long i64;
typedef long i64x2 __attribute__((ext_vector_type(2)));
typedef unsigned int u32;
typedef unsigned char u8;
typedef unsigned short u16;

__device__ __forceinline__ f32x4 mfma16(bf16x8 a, bf16x8 b, f32x4 c) {
    return __builtin_amdgcn_mfma_f32_16x16x32_bf16(a, b, c, 0, 0, 0);
}
__device__ __forceinline__ f32x4 mfma_fp8(i64 a, i64 b, f32x4 c) {
    return __builtin_amdgcn_mfma_f32_16x16x32_fp8_fp8(a, b, c, 0, 0, 0);
}

typedef __attribute__((address_space(1))) const void* gas_t;
typedef __attribute__((address_space(3))) void* las_t;
__device__ __forceinline__ void gl2lds16(const void* g, void* l) {
    __builtin_amdgcn_global_load_lds((gas_t)g, (las_t)l, 16, 0, 0);
}

// Manual f32 -> OCP e4m3fn converter. Verified by hand:
//   1.0 -> 0x38, 448 -> 0x7E, 0.02 -> 0x0A, <2^-6-half-ulp -> 0 (FTZ),
//   mantissa-carry on rounding handled by integer add, inf/garbage clamps
//   to 0x7E. CANNOT produce NaN encodings (0x7F/0xFF) for any input.
__device__ __forceinline__ u32 f32_to_fp8(float x) {
    union { float f; u32 u; } c;
    c.f = x;
    u32 s = (c.u >> 24) & 0x80;
    u32 m = (c.u & 0x7fffffff) + 0x00080000;  // round half-away at new LSB (bit 20)
    int e = (int)(m >> 23) - 127;
    if (e < -6) return s;                      // flush-to-zero
    if (e > 8) return s | 0x7e;                // clamp to 448 (covers inf/NaN input)
    u32 v = ((u32)(e + 7) << 3) | ((m >> 20) & 7);
    if (v > 0x7e) v = 0x7e;                    // 448<x<464 would hit 0x7F=NaN
    return s | v;
}
__device__ __forceinline__ u32 pk4_fp8(float a, float b, float c, float d) {
    return f32_to_fp8(a) | (f32_to_fp8(b) << 8) | (f32_to_fp8(c) << 16) |
           (f32_to_fp8(d) << 24);
}
__device__ __forceinline__ float bf2f(u16 v) {
    union { u32 u; float f; } cv;
    cv.u = (u32)v << 16;
    return cv.f;
}

// ---------------------------------------------------------------------------
// Kernel 1: GroupNorm statistics. One block per (batch, group).
// ---------------------------------------------------------------------------
__global__ __launch_bounds__(256) void gn_stats(const float* __restrict__ x,
                                                float* __restrict__ gstats) {
    int blk = blockIdx.x;  // b*32 + g
    int b = blk >> 5, g = blk & 31;
    int tid = threadIdx.x;
    int c = g * 8 + (tid >> 5);
    const float* row = x + ((size_t)(b * C_ + c)) * N_;
    float s = 0.f, s2 = 0.f;
    for (int n = (tid & 31) * 4; n < N_; n += 128) {
        float4 v = *(const float4*)(row + n);
        s += v.x + v.y + v.z + v.w;
        s2 += v.x * v.x + v.y * v.y + v.z * v.z + v.w * v.w;
    }
    for (int off = 32; off; off >>= 1) {
        s += __shfl_xor(s, off);
        s2 += __shfl_xor(s2, off);
    }
    __shared__ float red[8];
    int wid = tid >> 6;
    if ((tid & 63) == 0) { red[wid] = s; red[4 + wid] = s2; }
    __syncthreads();
    if (tid == 0) {
        float S = red[0] + red[1] + red[2] + red[3];
        float S2 = red[4] + red[5] + red[6] + red[7];
        float mean = S * (1.f / 32768.f);
        float var = S2 * (1.f / 32768.f) - mean * mean;
        gstats[blk * 2] = mean;
        gstats[blk * 2 + 1] = rsqrtf(var + 1e-6f);
    }
}

// ---------------------------------------------------------------------------
// Kernel 2: apply GroupNorm + transpose [b][c][n] fp32 -> [b*n][c] bf16.
// ---------------------------------------------------------------------------
__global__ __launch_bounds__(256) void gn_apply(const float* __restrict__ x,
                                                const float* __restrict__ gsc,
                                                const float* __restrict__ gbi,
                                                const float* __restrict__ gstats,
                                                bf16* __restrict__ hn) {
    __shared__ float tile[32][33];
    int b = blockIdx.z, c0 = blockIdx.y * 32, n0 = blockIdx.x * 32;
    int tx = threadIdx.x & 31, ty = threadIdx.x >> 5;
    for (int i = 0; i < 4; i++) {
        int cl = ty + i * 8;
        int c = c0 + cl;
        int g = c >> 3;
        float mean = gstats[(b * G_ + g) * 2];
        float rstd = gstats[(b * G_ + g) * 2 + 1];
        float sc = gsc[c] * rstd;
        float bs = gbi[c] - mean * sc;
        float v = x[((size_t)(b * C_ + c)) * N_ + n0 + tx];
        tile[cl][tx] = v * sc + bs;
    }
    __syncthreads();
    for (int i = 0; i < 4; i++) {
        int nl = ty + i * 8;
        hn[((size_t)(b * N_ + n0 + nl)) * C_ + c0 + tx] = (bf16)tile[tx][nl];
    }
}

// ---------------------------------------------------------------------------
// Kernel 3: convert the four 256x256 fp32 weight matrices to bf16 once.
// ---------------------------------------------------------------------------
__global__ __launch_bounds__(256) void cvt_w(const float* __restrict__ wq,
                                             const float* __restrict__ wk,
                                             const float* __restrict__ wv,
                                             const float* __restrict__ wp,
                                             bf16* __restrict__ dst) {
    int i = blockIdx.x * 256 + threadIdx.x;
    dst[i] = (bf16)wq[i];
    dst[65536 + i] = (bf16)wk[i];
    dst[131072 + i] = (bf16)wv[i];
    dst[196608 + i] = (bf16)wp[i];
}

// ---------------------------------------------------------------------------
// Kernel 4: merged Q+K NT GEMM, token-major bf16 outputs.
// ---------------------------------------------------------------------------
__global__ __launch_bounds__(256) void gemm_qk(const bf16* __restrict__ A,
                                               const bf16* __restrict__ Wq,
                                               const bf16* __restrict__ Wk,
                                               const float* __restrict__ bq,
                                               const float* __restrict__ bk,
                                               bf16* __restrict__ qout,
                                               bf16* __restrict__ kout) {
    __shared__ __align__(16) bf16 As[64][32];
    __shared__ __align__(16) bf16 Wqs[64][32];
    __shared__ __align__(16) bf16 Wks[64][32];
    int m0 = blockIdx.x * 64, n0 = blockIdx.y * 64;
    int tid = threadIdx.x;
    int wv = tid >> 6, lane = tid & 63, lr = lane & 15, lq = lane >> 4;
    int wm = (wv & 1) * 32, wn = (wv >> 1) * 32;
    int sr = tid >> 2, sk = (tid & 3) * 8;
    f32x4 qacc[2][2] = {}, kacc[2][2] = {};
    for (int kk = 0; kk < C_; kk += 32) {
        __syncthreads();
        *(bf16x8*)&As[sr][sk] = *(const bf16x8*)&A[(size_t)(m0 + sr) * C_ + kk + sk];
        *(bf16x8*)&Wqs[sr][sk] = *(const bf16x8*)&Wq[(size_t)(n0 + sr) * C_ + kk + sk];
        *(bf16x8*)&Wks[sr][sk] = *(const bf16x8*)&Wk[(size_t)(n0 + sr) * C_ + kk + sk];
        __syncthreads();
        bf16x8 a0 = *(const bf16x8*)&As[wm + lr][lq * 8];
        bf16x8 a1 = *(const bf16x8*)&As[wm + 16 + lr][lq * 8];
        bf16x8 q0 = *(const bf16x8*)&Wqs[wn + lr][lq * 8];
        bf16x8 q1 = *(const bf16x8*)&Wqs[wn + 16 + lr][lq * 8];
        bf16x8 k0 = *(const bf16x8*)&Wks[wn + lr][lq * 8];
        bf16x8 k1 = *(const bf16x8*)&Wks[wn + 16 + lr][lq * 8];
        qacc[0][0] = mfma16(a0, q0, qacc[0][0]);
        qacc[0][1] = mfma16(a0, q1, qacc[0][1]);
        qacc[1][0] = mfma16(a1, q0, qacc[1][0]);
        qacc[1][1] = mfma16(a1, q1, qacc[1][1]);
        kacc[0][0] = mfma16(a0, k0, kacc[0][0]);
        kacc[0][1] = mfma16(a0, k1, kacc[0][1]);
        kacc[1][0] = mfma16(a1, k0, kacc[1][0]);
        kacc[1][1] = mfma16(a1, k1, kacc[1][1]);
    }
    for (int i = 0; i < 2; i++)
        for (int j = 0; j < 2; j++) {
            int col = n0 + wn + j * 16 + lr;
            float bvq = bq[col], bvk = bk[col];
            for (int r = 0; r < 4; r++) {
                int row = m0 + wm + i * 16 + lq * 4 + r;
                qout[(size_t)row * C_ + col] = (bf16)(qacc[i][j][r] + bvq);
                kout[(size_t)row * C_ + col] = (bf16)(kacc[i][j][r] + bvk);
            }
        }
}

// ---------------------------------------------------------------------------
// Kernel 5: NT GEMM, channel-major bf16 output (V^T).
// ---------------------------------------------------------------------------
__global__ __launch_bounds__(256) void gemm_nt_ch(const bf16* __restrict__ W,
                                                  const bf16* __restrict__ A,
                                                  const float* __restrict__ bias,
                                                  bf16* __restrict__ outT) {
    __shared__ __align__(16) bf16 Ws[64][32];
    __shared__ __align__(16) bf16 As[64][32];
    int m0 = blockIdx.x * 64;  // o
    int n0 = blockIdx.y * 64;  // token
    int tid = threadIdx.x;
    int wv = tid >> 6, lane = tid & 63, lr = lane & 15, lq = lane >> 4;
    int wm = (wv & 1) * 32, wn = (wv >> 1) * 32;
    int sr = tid >> 2, sk = (tid & 3) * 8;
    f32x4 acc[2][2] = {};
    for (int kk = 0; kk < C_; kk += 32) {
        __syncthreads();
        *(bf16x8*)&Ws[sr][sk] = *(const bf16x8*)&W[(size_t)(m0 + sr) * C_ + kk + sk];
        *(bf16x8*)&As[sr][sk] = *(const bf16x8*)&A[(size_t)(n0 + sr) * C_ + kk + sk];
        __syncthreads();
        bf16x8 a0 = *(const bf16x8*)&Ws[wm + lr][lq * 8];
        bf16x8 a1 = *(const bf16x8*)&Ws[wm + 16 + lr][lq * 8];
        bf16x8 b0 = *(const bf16x8*)&As[wn + lr][lq * 8];
        bf16x8 b1 = *(const bf16x8*)&As[wn + 16 + lr][lq * 8];
        acc[0][0] = mfma16(a0, b0, acc[0][0]);
        acc[0][1] = mfma16(a0, b1, acc[0][1]);
        acc[1][0] = mfma16(a1, b0, acc[1][0]);
        acc[1][1] = mfma16(a1, b1, acc[1][1]);
    }
    for (int i = 0; i < 2; i++)
        for (int j = 0; j < 2; j++) {
            int T = n0 + wn + j * 16 + lr;
            int b = T >> 12, n = T & (N_ - 1);
            for (int r = 0; r < 4; r++) {
                int o = m0 + wm + i * 16 + lq * 4 + r;
                outT[((size_t)(b * C_ + o)) * N_ + n] = (bf16)(acc[i][j][r] + bias[o]);
            }
        }
}

// ---------------------------------------------------------------------------
// Kernel 5b: bf16 Q/K -> fp8, sigma channel permutation baked in:
//   phys p = [tq:2][lq:2][par:1][j:3]  <->  logical c = [tq:2][par:1][lq:2][j:3]
// so an attn-side b128 load at col tq*64+lq*16 yields the lane's 8-byte
// pieces of k-steps 2tq and 2tq+1 contiguously.
// ---------------------------------------------------------------------------
__global__ __launch_bounds__(256) void cvt_qk(const bf16* __restrict__ qb,
                                              const bf16* __restrict__ kb,
                                              u8* __restrict__ q8,
                                              u8* __restrict__ k8) {
    int idx = (blockIdx.x * 256 + threadIdx.x) * 4;  // byte pos, 4-aligned
    int row = idx >> 8;
    int p = idx & 255;
    int c = (p & 0xC0) | ((p & 8) << 2) | ((p >> 1) & 0x18) | (p & 7);
    const u16* qs = (const u16*)&qb[(size_t)row * 256 + c];
    const u16* ks = (const u16*)&kb[(size_t)row * 256 + c];
    ushort4 qv = *(const ushort4*)qs;
    ushort4 kv = *(const ushort4*)ks;
    *(u32*)&q8[idx] = pk4_fp8(bf2f(qv.x), bf2f(qv.y), bf2f(qv.z), bf2f(qv.w));
    *(u32*)&k8[idx] = pk4_fp8(bf2f(kv.x), bf2f(kv.y), bf2f(kv.z), bf2f(kv.w));
}

// ---------------------------------------------------------------------------
// Kernel 5c: bf16 V^T -> fp8, pi key permutation within each 64-key block:
// pos = (n&15)*4 + ((n>>4)&3). P-writes become packed b32 and P/V fragment
// reads aligned b64.
// ---------------------------------------------------------------------------
__global__ __launch_bounds__(256) void cvt_v(const bf16* __restrict__ vT,
                                             u8* __restrict__ v8) {
    int idx = (blockIdx.x * 256 + threadIdx.x) * 4;  // element index, 4-aligned
    int n = idx & 4095;
    int rowbase = idx & ~4095;
    ushort4 v = *(const ushort4*)&vT[idx];
    int pb = rowbase + (n & ~63) + ((n >> 4) & 3);
    int nl = n & 15;
    v8[pb + (nl + 0) * 4] = (u8)f32_to_fp8(bf2f(v.x));
    v8[pb + (nl + 1) * 4] = (u8)f32_to_fp8(bf2f(v.y));
    v8[pb + (nl + 2) * 4] = (u8)f32_to_fp8(bf2f(v.z));
    v8[pb + (nl + 3) * 4] = (u8)f32_to_fp8(bf2f(v.w));
}

// ---------------------------------------------------------------------------
// Kernel 6: fp8 flash attention, fixed-max softmax, 64-key tiles.
//   2 waves / 64 q per block, 512 blocks = 2 independent blocks/CU. All
//   K/V/P data fp8 => LDS bytes per (q,k) halved vs R3; 64-key tiles +
//   sigma/pi permutations => K-frags b128, V/P-frags b64, P-writes b32.
// ---------------------------------------------------------------------------
__global__ __launch_bounds__(128, 1) void attn(const u8* __restrict__ q,
                                               const u8* __restrict__ k,
                                               const u8* __restrict__ vT,
                                               bf16* __restrict__ hm) {
    __shared__ __align__(16) u8 smem[70144];
    u8* Ks = smem;           // [2][64*256] fp8 = 32 KB
    u8* Vt = smem + 32768;   // [2][256*64] fp8 = 32 KB
    u8* Ps = smem + 65536;   // [2 waves][32 rows * 72 B] = 4.5 KB

    int b = blockIdx.y, q0 = blockIdx.x * 64;
    int tid = threadIdx.x;
    int w = tid >> 6, lane = tid & 63, lr = lane & 15, lq = lane >> 4;

    const u8* kglob = k + (size_t)b * N_ * C_;
    const u8* vglob = vT + (size_t)b * C_ * N_;

    // Staging offsets. K tile: 1024 16B-chunks; chunk p -> row r=p>>4, phys
    // chunk p&15, global chunk (p&15)^(r&15). V: p -> row p>>2, global chunk
    // (p&3)^((p>>2)&3).
    u32 offK[8], offV[8];
#pragma unroll
    for (int j = 0; j < 8; j++) {
        int p = ((w * 8 + j) << 6) + lane;
        int rK = p >> 4, cK = (p & 15) ^ (rK & 15);
        offK[j] = rK * 256 + cK * 16;
        int rV = p >> 2, cV = (p & 3) ^ (rV & 3);
        offV[j] = rV * N_ + cV * 16;
    }

    // Q fragments (fp8, sigma-permuted): [subtile t][tq] b128 = k-steps 2tq,2tq+1.
    i64x2 qf[2][4];
#pragma unroll
    for (int t = 0; t < 2; t++) {
        const u8* qrow = q + ((size_t)(b * N_ + q0 + w * 32 + t * 16 + lr)) * 256;
#pragma unroll
        for (int tq = 0; tq < 4; tq++)
            qf[t][tq] = *(const i64x2*)&qrow[tq * 64 + lq * 16];
    }

    f32x4 oacc[2][16] = {};
    float li[2][4] = {};
    u8* Pw = Ps + w * 2304;

    // Prologue: stage tile 0 into buffer 0.
#pragma unroll
    for (int j = 0; j < 8; j++) {
        gl2lds16(kglob + offK[j], Ks + ((w * 8 + j) << 10));
        gl2lds16(vglob + offV[j], Vt + ((w * 8 + j) << 10));
    }

    for (int mt = 0; mt < 64; mt++) {
        int cur = mt & 1;
        __syncthreads();

        if (mt < 63) {
            const u8* kit = kglob + (size_t)(mt + 1) * 64 * 256;
            const u8* vit = vglob + (mt + 1) * 64;
#pragma unroll
            for (int j = 0; j < 8; j++) {
                gl2lds16(kit + offK[j], Ks + (cur ^ 1) * 16384 + ((w * 8 + j) << 10));
                gl2lds16(vit + offV[j], Vt + (cur ^ 1) * 16384 + ((w * 8 + j) << 10));
            }
        }

        const u8* Kb = Ks + cur * 16384;
        const u8* Vb = Vt + cur * 16384;

        // --- S = Q K^T: 32 queries x 64 keys (2 q-subtiles x 4 k-subtiles) ---
        f32x4 st[2][4] = {};
#pragma unroll
        for (int kt = 0; kt < 4; kt++) {
            int r = kt * 16 + lr;
#pragma unroll
            for (int tq = 0; tq < 4; tq++) {
                i64x2 kf = *(const i64x2*)&Kb[r * 256 + (((tq * 4 + lq) ^ (r & 15)) << 4)];
                st[0][kt] = mfma_fp8(qf[0][tq].x, kf.x, st[0][kt]);
                st[0][kt] = mfma_fp8(qf[0][tq].y, kf.y, st[0][kt]);
                st[1][kt] = mfma_fp8(qf[1][tq].x, kf.x, st[1][kt]);
                st[1][kt] = mfma_fp8(qf[1][tq].y, kf.y, st[1][kt]);
            }
        }

        // --- fixed-max softmax numerators -> fp8 P (packed b32 writes) ---
#pragma unroll
        for (int t = 0; t < 2; t++)
#pragma unroll
            for (int r = 0; r < 4; r++) {
                float e0 = __expf(st[t][0][r] * 0.0625f);
                float e1 = __expf(st[t][1][r] * 0.0625f);
                float e2 = __expf(st[t][2][r] * 0.0625f);
                float e3 = __expf(st[t][3][r] * 0.0625f);
                li[t][r] += (e0 + e1) + (e2 + e3);
                *(u32*)&Pw[(t * 16 + lq * 4 + r) * 72 + lr * 4] = pk4_fp8(e0, e1, e2, e3);
            }

        // --- PV: P (32x64) x V (64x256) ---
        i64 pf[2][2];
#pragma unroll
        for (int t = 0; t < 2; t++)
#pragma unroll
            for (int u = 0; u < 2; u++)
                pf[t][u] = *(const i64*)&Pw[(t * 16 + lr) * 72 + u * 32 + lq * 8];
#pragma unroll
        for (int ct = 0; ct < 16; ct++) {
            int row = ct * 16 + lr;
            int base = row * 64 + ((lq & 1) << 3);
            i64 vf0 = *(const i64*)&Vb[base + ((((lq >> 1) + 0) ^ (row & 3)) << 4)];
            i64 vf1 = *(const i64*)&Vb[base + ((((lq >> 1) + 2) ^ (row & 3)) << 4)];
            oacc[0][ct] = mfma_fp8(pf[0][0], vf0, oacc[0][ct]);
            oacc[0][ct] = mfma_fp8(pf[0][1], vf1, oacc[0][ct]);
            oacc[1][ct] = mfma_fp8(pf[1][0], vf0, oacc[1][ct]);
            oacc[1][ct] = mfma_fp8(pf[1][1], vf1, oacc[1][ct]);
        }
    }

    // Final l reduction across the 16 lr-lanes (keys partitioned by lr).
    float inv[2][4];
#pragma unroll
    for (int t = 0; t < 2; t++)
#pragma unroll
        for (int r = 0; r < 4; r++) {
            float s = li[t][r];
            s += __shfl_xor(s, 1);
            s += __shfl_xor(s, 2);
            s += __shfl_xor(s, 4);
            s += __shfl_xor(s, 8);
            inv[t][r] = 1.f / s;
        }
#pragma unroll
    for (int t = 0; t < 2; t++)
#pragma unroll
        for (int ct = 0; ct < 16; ct++)
#pragma unroll
            for (int r = 0; r < 4; r++)
                hm[((size_t)(b * N_ + q0 + w * 32 + t * 16 + lq * 4 + r)) * C_ + ct * 16 + lr] =
                    (bf16)(oacc[t][ct][r] * inv[t][r]);
}

// ---------------------------------------------------------------------------
// Kernel 7: proj + residual.
// ---------------------------------------------------------------------------
__global__ __launch_bounds__(256) void proj_res(const bf16* __restrict__ W,
                                                const bf16* __restrict__ A,
                                                const float* __restrict__ bias,
                                                const float* __restrict__ x,
                                                float* __restrict__ out) {
    __shared__ __align__(16) bf16 Ws[64][32];
    __shared__ __align__(16) bf16 As[64][32];
    int m0 = blockIdx.x * 64;  // o
    int n0 = blockIdx.y * 64;  // token
    int tid = threadIdx.x;
    int wv = tid >> 6, lane = tid & 63, lr = lane & 15, lq = lane >> 4;
    int wm = (wv & 1) * 32, wn = (wv >> 1) * 32;
    int sr = tid >> 2, sk = (tid & 3) * 8;
    f32x4 acc[2][2] = {};
    for (int kk = 0; kk < C_; kk += 32) {
        __syncthreads();
        *(bf16x8*)&Ws[sr][sk] = *(const bf16x8*)&W[(size_t)(m0 + sr) * C_ + kk + sk];
        *(bf16x8*)&As[sr][sk] = *(const bf16x8*)&A[(size_t)(n0 + sr) * C_ + kk + sk];
        __syncthreads();
        bf16x8 a0 = *(const bf16x8*)&Ws[wm + lr][lq * 8];
        bf16x8 a1 = *(const bf16x8*)&Ws[wm + 16 + lr][lq * 8];
        bf16x8 b0 = *(const bf16x8*)&As[wn + lr][lq * 8];
        bf16x8 b1 = *(const bf16x8*)&As[wn + 16 + lr][lq * 8];
        acc[0][0] = mfma16(a0, b0, acc[0][0]);
        acc[0][1] = mfma16(a0, b1, acc[0][1]);
        acc[1][0] = mfma16(a1, b0, acc[1][0]);
        acc[1][1] = mfma16(a1, b1, acc[1][1]);
    }
    for (int i = 0; i < 2; i++)
        for (int j = 0; j < 2; j++) {
            int T = n0 + wn + j * 16 + lr;
            int b = T >> 12, n = T & (N_ - 1);
            for (int r = 0; r < 4; r++) {
                int o = m0 + wm + i * 16 + lq * 4 + r;
                size_t idx = ((size_t)(b * C_ + o)) * N_ + n;
                out[idx] = x[idx] + acc[i][j][r] + bias[o];
            }
        }
}

// ---------------------------------------------------------------------------
extern "C" void kernel_launch(void* const* d_in, const int* in_sizes, int n_in,
                              void* d_out, int out_size, void* d_ws, size_t ws_size,
                              hipStream_t stream) {
    const float* x = (const float*)d_in[0];
    const float* gsc = (const float*)d_in[1];
    const float* gbi = (const float*)d_in[2];
    const float* wq = (const float*)d_in[3];
    const float* bq = (const float*)d_in[4];
    const float* wk = (const float*)d_in[5];
    const float* bk = (const float*)d_in[6];
    const float* wv = (const float*)d_in[7];
    const float* bv = (const float*)d_in[8];
    const float* wp = (const float*)d_in[9];
    const float* bp = (const float*)d_in[10];
    float* out = (float*)d_out;

    const size_t SZ = (size_t)B_ * N_ * C_;    // 8388608 elements
    const size_t BUF = SZ * 2;                  // bf16 buffer bytes
    char* ws = (char*)d_ws;
    float* gstats = (float*)ws;                 // 4 KB
    bf16* wb = (bf16*)(ws + 4096);              // 512 KB
    char* hnB = ws + 4096 + 524288;             // bf16 hn  [BUF]
    char* qbB = hnB + BUF;                      // bf16 qb  [BUF]
    char* kbB = qbB + BUF;                      // bf16 kb  [BUF]
    char* vTB = kbB + BUF;                      // bf16 vT  [BUF]
    bf16* hn = (bf16*)hnB;
    bf16* qb = (bf16*)qbB;
    bf16* kb = (bf16*)kbB;
    bf16* vT = (bf16*)vTB;
    // fp8 buffers alias dead bf16 regions:
    u8* q8 = (u8*)hnB;            // hn dead after both GEMMs
    u8* k8 = (u8*)(hnB + SZ);
    u8* v8 = (u8*)kbB;            // kb dead after cvt_qk
    bf16* hm = (bf16*)qbB;        // qb dead after cvt_qk

    cvt_w<<<256, 256, 0, stream>>>(wq, wk, wv, wp, wb);
    gn_stats<<<B_ * G_, 256, 0, stream>>>(x, gstats);
    gn_apply<<<dim3(N_ / 32, C_ / 32, B_), 256, 0, stream>>>(x, gsc, gbi, gstats, hn);
    gemm_qk<<<dim3(B_ * N_ / 64, C_ / 64), 256, 0, stream>>>(hn, wb, wb + 65536, bq, bk, qb, kb);
    gemm_nt_ch<<<dim3(C_ / 64, B_ * N_ / 64), 256, 0, stream>>>(wb + 131072, hn, bv, vT);
    cvt_qk<<<8192, 256, 0, stream>>>(qb, kb, q8, k8);
    cvt_v<<<8192, 256, 0, stream>>>(vT, v8);
    attn<<<dim3(N_ / 64, B_), 128, 0, stream>>>(q8, k8, v8, hm);
    proj_res<<<dim3(C_ / 64, B_ * N_ / 64), 256, 0, stream>>>(wb + 196608, hm, bp, x, out);
}

// Round 8
// 322.389 us; speedup vs baseline: 1.7265x; 1.4107x over previous
//
#include <hip/hip_runtime.h>

#define B_ 8
#define C_ 256
#define N_ 4096
#define G_ 32

typedef __bf16 bf16;
typedef __bf16 bf16x8 __attribute__((ext_vector_type(8)));
typedef float f32x4 __attribute__((ext_vector_type(4)));
typedef long i64;
typedef long i64x2 __attribute__((ext_vector_type(2)));
typedef unsigned int u32;
typedef unsigned char u8;
typedef unsigned short u16;
// may_alias types for the P LDS round-trip: the u16 stores and i64 loads hit
// the same bytes; without this TBAA lets the compiler hoist the ds_read above
// the ds_write (R7's NaN: stale LDS bytes -> fp8 NaN encodings -> MFMA NaN).
typedef unsigned short __attribute__((may_alias)) u16a;
typedef long __attribute__((may_alias)) i64a;

__device__ __forceinline__ f32x4 mfma16(bf16x8 a, bf16x8 b, f32x4 c) {
    return __builtin_amdgcn_mfma_f32_16x16x32_bf16(a, b, c, 0, 0, 0);
}
__device__ __forceinline__ f32x4 mfma_fp8(i64 a, i64 b, f32x4 c) {
    return __builtin_amdgcn_mfma_f32_16x16x32_fp8_fp8(a, b, c, 0, 0, 0);
}

typedef __attribute__((address_space(1))) const void* gas_t;
typedef __attribute__((address_space(3))) void* las_t;
__device__ __forceinline__ void gl2lds16(const void* g, void* l) {
    __builtin_amdgcn_global_load_lds((gas_t)g, (las_t)l, 16, 0, 0);
}

// Full-range f32 -> OCP e4m3fn (NaN-free by construction). Used in cvt kernels.
__device__ __forceinline__ u32 f32_to_fp8(float x) {
    union { float f; u32 u; } c;
    c.f = x;
    u32 s = (c.u >> 24) & 0x80;
    u32 m = (c.u & 0x7fffffff) + 0x00080000;
    int e = (int)(m >> 23) - 127;
    if (e < -6) return s;
    if (e > 8) return s | 0x7e;
    u32 v = ((u32)(e + 7) << 3) | ((m >> 20) & 7);
    if (v > 0x7e) v = 0x7e;
    return s | v;
}
__device__ __forceinline__ u32 pk4_fp8(float a, float b, float c, float d) {
    return f32_to_fp8(a) | (f32_to_fp8(b) << 8) | (f32_to_fp8(c) << 16) |
           (f32_to_fp8(d) << 24);
}
// 3-op converter for known-positive x in [2^-6, 2^8): exp() outputs only.
// Identical to f32_to_fp8 on that range (verified algebraically).
__device__ __forceinline__ u32 fp8_fast(float x) {
    union { float f; u32 u; } c;
    c.f = x;
    return ((c.u + 0x00080000u) >> 20) - 960u;  // low 8 bits valid
}
__device__ __forceinline__ float bf2f(u16 v) {
    union { u32 u; float f; } cv;
    cv.u = (u32)v << 16;
    return cv.f;
}

// ---------------------------------------------------------------------------
// Kernel 1: GroupNorm statistics. One block per (batch, group).
// ---------------------------------------------------------------------------
__global__ __launch_bounds__(256) void gn_stats(const float* __restrict__ x,
                                                float* __restrict__ gstats) {
    int blk = blockIdx.x;  // b*32 + g
    int b = blk >> 5, g = blk & 31;
    int tid = threadIdx.x;
    int c = g * 8 + (tid >> 5);
    const float* row = x + ((size_t)(b * C_ + c)) * N_;
    float s = 0.f, s2 = 0.f;
    for (int n = (tid & 31) * 4; n < N_; n += 128) {
        float4 v = *(const float4*)(row + n);
        s += v.x + v.y + v.z + v.w;
        s2 += v.x * v.x + v.y * v.y + v.z * v.z + v.w * v.w;
    }
    for (int off = 32; off; off >>= 1) {
        s += __shfl_xor(s, off);
        s2 += __shfl_xor(s2, off);
    }
    __shared__ float red[8];
    int wid = tid >> 6;
    if ((tid & 63) == 0) { red[wid] = s; red[4 + wid] = s2; }
    __syncthreads();
    if (tid == 0) {
        float S = red[0] + red[1] + red[2] + red[3];
        float S2 = red[4] + red[5] + red[6] + red[7];
        float mean = S * (1.f / 32768.f);
        float var = S2 * (1.f / 32768.f) - mean * mean;
        gstats[blk * 2] = mean;
        gstats[blk * 2 + 1] = rsqrtf(var + 1e-6f);
    }
}

// ---------------------------------------------------------------------------
// Kernel 2: apply GroupNorm + transpose [b][c][n] fp32 -> [b*n][c] bf16.
// ---------------------------------------------------------------------------
__global__ __launch_bounds__(256) void gn_apply(const float* __restrict__ x,
                                                const float* __restrict__ gsc,
                                                const float* __restrict__ gbi,
                                                const float* __restrict__ gstats,
                                                bf16* __restrict__ hn) {
    __shared__ float tile[32][33];
    int b = blockIdx.z, c0 = blockIdx.y * 32, n0 = blockIdx.x * 32;
    int tx = threadIdx.x & 31, ty = threadIdx.x >> 5;
    for (int i = 0; i < 4; i++) {
        int cl = ty + i * 8;
        int c = c0 + cl;
        int g = c >> 3;
        float mean = gstats[(b * G_ + g) * 2];
        float rstd = gstats[(b * G_ + g) * 2 + 1];
        float sc = gsc[c] * rstd;
        float bs = gbi[c] - mean * sc;
        float v = x[((size_t)(b * C_ + c)) * N_ + n0 + tx];
        tile[cl][tx] = v * sc + bs;
    }
    __syncthreads();
    for (int i = 0; i < 4; i++) {
        int nl = ty + i * 8;
        hn[((size_t)(b * N_ + n0 + nl)) * C_ + c0 + tx] = (bf16)tile[tx][nl];
    }
}

// ---------------------------------------------------------------------------
// Kernel 3: convert the four 256x256 fp32 weight matrices to bf16 once.
// ---------------------------------------------------------------------------
__global__ __launch_bounds__(256) void cvt_w(const float* __restrict__ wq,
                                             const float* __restrict__ wk,
                                             const float* __restrict__ wv,
                                             const float* __restrict__ wp,
                                             bf16* __restrict__ dst) {
    int i = blockIdx.x * 256 + threadIdx.x;
    dst[i] = (bf16)wq[i];
    dst[65536 + i] = (bf16)wk[i];
    dst[131072 + i] = (bf16)wv[i];
    dst[196608 + i] = (bf16)wp[i];
}

// ---------------------------------------------------------------------------
// Kernel 4: merged Q+K NT GEMM, token-major bf16 outputs.
// ---------------------------------------------------------------------------
__global__ __launch_bounds__(256) void gemm_qk(const bf16* __restrict__ A,
                                               const bf16* __restrict__ Wq,
                                               const bf16* __restrict__ Wk,
                                               const float* __restrict__ bq,
                                               const float* __restrict__ bk,
                                               bf16* __restrict__ qout,
                                               bf16* __restrict__ kout) {
    __shared__ __align__(16) bf16 As[64][32];
    __shared__ __align__(16) bf16 Wqs[64][32];
    __shared__ __align__(16) bf16 Wks[64][32];
    int m0 = blockIdx.x * 64, n0 = blockIdx.y * 64;
    int tid = threadIdx.x;
    int wv = tid >> 6, lane = tid & 63, lr = lane & 15, lq = lane >> 4;
    int wm = (wv & 1) * 32, wn = (wv >> 1) * 32;
    int sr = tid >> 2, sk = (tid & 3) * 8;
    f32x4 qacc[2][2] = {}, kacc[2][2] = {};
    for (int kk = 0; kk < C_; kk += 32) {
        __syncthreads();
        *(bf16x8*)&As[sr][sk] = *(const bf16x8*)&A[(size_t)(m0 + sr) * C_ + kk + sk];
        *(bf16x8*)&Wqs[sr][sk] = *(const bf16x8*)&Wq[(size_t)(n0 + sr) * C_ + kk + sk];
        *(bf16x8*)&Wks[sr][sk] = *(const bf16x8*)&Wk[(size_t)(n0 + sr) * C_ + kk + sk];
        __syncthreads();
        bf16x8 a0 = *(const bf16x8*)&As[wm + lr][lq * 8];
        bf16x8 a1 = *(const bf16x8*)&As[wm + 16 + lr][lq * 8];
        bf16x8 q0 = *(const bf16x8*)&Wqs[wn + lr][lq * 8];
        bf16x8 q1 = *(const bf16x8*)&Wqs[wn + 16 + lr][lq * 8];
        bf16x8 k0 = *(const bf16x8*)&Wks[wn + lr][lq * 8];
        bf16x8 k1 = *(const bf16x8*)&Wks[wn + 16 + lr][lq * 8];
        qacc[0][0] = mfma16(a0, q0, qacc[0][0]);
        qacc[0][1] = mfma16(a0, q1, qacc[0][1]);
        qacc[1][0] = mfma16(a1, q0, qacc[1][0]);
        qacc[1][1] = mfma16(a1, q1, qacc[1][1]);
        kacc[0][0] = mfma16(a0, k0, kacc[0][0]);
        kacc[0][1] = mfma16(a0, k1, kacc[0][1]);
        kacc[1][0] = mfma16(a1, k0, kacc[1][0]);
        kacc[1][1] = mfma16(a1, k1, kacc[1][1]);
    }
    for (int i = 0; i < 2; i++)
        for (int j = 0; j < 2; j++) {
            int col = n0 + wn + j * 16 + lr;
            float bvq = bq[col], bvk = bk[col];
            for (int r = 0; r < 4; r++) {
                int row = m0 + wm + i * 16 + lq * 4 + r;
                qout[(size_t)row * C_ + col] = (bf16)(qacc[i][j][r] + bvq);
                kout[(size_t)row * C_ + col] = (bf16)(kacc[i][j][r] + bvk);
            }
        }
}

// ---------------------------------------------------------------------------
// Kernel 5: NT GEMM, channel-major bf16 output (V^T).
// ---------------------------------------------------------------------------
__global__ __launch_bounds__(256) void gemm_nt_ch(const bf16* __restrict__ W,
                                                  const bf16* __restrict__ A,
                                                  const float* __restrict__ bias,
                                                  bf16* __restrict__ outT) {
    __shared__ __align__(16) bf16 Ws[64][32];
    __shared__ __align__(16) bf16 As[64][32];
    int m0 = blockIdx.x * 64;  // o
    int n0 = blockIdx.y * 64;  // token
    int tid = threadIdx.x;
    int wv = tid >> 6, lane = tid & 63, lr = lane & 15, lq = lane >> 4;
    int wm = (wv & 1) * 32, wn = (wv >> 1) * 32;
    int sr = tid >> 2, sk = (tid & 3) * 8;
    f32x4 acc[2][2] = {};
    for (int kk = 0; kk < C_; kk += 32) {
        __syncthreads();
        *(bf16x8*)&Ws[sr][sk] = *(const bf16x8*)&W[(size_t)(m0 + sr) * C_ + kk + sk];
        *(bf16x8*)&As[sr][sk] = *(const bf16x8*)&A[(size_t)(n0 + sr) * C_ + kk + sk];
        __syncthreads();
        bf16x8 a0 = *(const bf16x8*)&Ws[wm + lr][lq * 8];
        bf16x8 a1 = *(const bf16x8*)&Ws[wm + 16 + lr][lq * 8];
        bf16x8 b0 = *(const bf16x8*)&As[wn + lr][lq * 8];
        bf16x8 b1 = *(const bf16x8*)&As[wn + 16 + lr][lq * 8];
        acc[0][0] = mfma16(a0, b0, acc[0][0]);
        acc[0][1] = mfma16(a0, b1, acc[0][1]);
        acc[1][0] = mfma16(a1, b0, acc[1][0]);
        acc[1][1] = mfma16(a1, b1, acc[1][1]);
    }
    for (int i = 0; i < 2; i++)
        for (int j = 0; j < 2; j++) {
            int T = n0 + wn + j * 16 + lr;
            int b = T >> 12, n = T & (N_ - 1);
            for (int r = 0; r < 4; r++) {
                int o = m0 + wm + i * 16 + lq * 4 + r;
                outT[((size_t)(b * C_ + o)) * N_ + n] = (bf16)(acc[i][j][r] + bias[o]);
            }
        }
}

// ---------------------------------------------------------------------------
// Kernel 5b: bf16 Q/K -> fp8, sigma channel permutation baked in.
// ---------------------------------------------------------------------------
__global__ __launch_bounds__(256) void cvt_qk(const bf16* __restrict__ qb,
                                              const bf16* __restrict__ kb,
                                              u8* __restrict__ q8,
                                              u8* __restrict__ k8) {
    int idx = (blockIdx.x * 256 + threadIdx.x) * 4;
    int row = idx >> 8;
    int p = idx & 255;
    int c = (p & 0xC0) | ((p & 8) << 2) | ((p >> 1) & 0x18) | (p & 7);
    const u16* qs = (const u16*)&qb[(size_t)row * 256 + c];
    const u16* ks = (const u16*)&kb[(size_t)row * 256 + c];
    ushort4 qv = *(const ushort4*)qs;
    ushort4 kv = *(const ushort4*)ks;
    *(u32*)&q8[idx] = pk4_fp8(bf2f(qv.x), bf2f(qv.y), bf2f(qv.z), bf2f(qv.w));
    *(u32*)&k8[idx] = pk4_fp8(bf2f(kv.x), bf2f(kv.y), bf2f(kv.z), bf2f(kv.w));
}

// ---------------------------------------------------------------------------
// Kernel 5c: bf16 V^T -> fp8, pi key permutation within each 32-key block:
// pos(n) = ((n&15)<<1) | ((n>>4)&1).
// ---------------------------------------------------------------------------
__global__ __launch_bounds__(256) void cvt_v(const bf16* __restrict__ vT,
                                             u8* __restrict__ v8) {
    int idx = (blockIdx.x * 256 + threadIdx.x) * 4;
    int n = idx & 4095;
    int rowbase = idx & ~4095;
    ushort4 v = *(const ushort4*)&vT[idx];
    int blk = rowbase + (n & ~31);
    int n0 = n & 31;
#define POS(nn) ((((nn) & 15) << 1) | (((nn) >> 4) & 1))
    v8[blk + POS(n0 + 0)] = (u8)f32_to_fp8(bf2f(v.x));
    v8[blk + POS(n0 + 1)] = (u8)f32_to_fp8(bf2f(v.y));
    v8[blk + POS(n0 + 2)] = (u8)f32_to_fp8(bf2f(v.z));
    v8[blk + POS(n0 + 3)] = (u8)f32_to_fp8(bf2f(v.w));
#undef POS
}

// ---------------------------------------------------------------------------
// Kernel 6: fp8 flash attention, fixed-max softmax, block-level split-K.
//   Each block: 2 waves, 64 queries, HALF the keys (2048) in 32-key tiles.
//   Grid 1024 = 4 blocks/CU (35 KB LDS) -> 2 independent waves/SIMD.
//   P round-trip: may_alias types + __threadfence_block() (the R7 NaN fix).
// ---------------------------------------------------------------------------
__global__ __launch_bounds__(128, 2) void attn(const u8* __restrict__ q,
                                               const u8* __restrict__ k,
                                               const u8* __restrict__ vT,
                                               bf16* __restrict__ O0,
                                               bf16* __restrict__ O1,
                                               float* __restrict__ lp) {
    __shared__ __align__(16) u8 smem[35840];
    u8* Ks = smem;           // [2][32*256] fp8 = 16 KB
    u8* Vt = smem + 16384;   // [2][256*32] fp8 = 16 KB
    u8* Ps = smem + 32768;   // [2 waves][32 rows * 48 B] = 3 KB

    int b = blockIdx.z, h = blockIdx.y, q0 = blockIdx.x * 64;
    int tid = threadIdx.x;
    int w = tid >> 6, lane = tid & 63, lr = lane & 15, lq = lane >> 4;

    const u8* kglob = k + ((size_t)(b * N_) + h * 2048) * 256;
    const u8* vglob = vT + (size_t)b * C_ * N_ + h * 2048;

    u32 offK[4], offV[4];
#pragma unroll
    for (int j = 0; j < 4; j++) {
        int p = ((w * 4 + j) << 6) + lane;  // 0..511
        int rK = p >> 4, cK = (p & 15) ^ (rK & 15);
        offK[j] = rK * 256 + cK * 16;
        int rV = p >> 1, cV = (p & 1) ^ ((rV >> 2) & 1);
        offV[j] = rV * N_ + cV * 16;
    }

    // Q fragments (fp8, sigma-permuted): [subtile t][tq] b128 = k-steps 2tq,2tq+1.
    i64x2 qf[2][4];
#pragma unroll
    for (int t = 0; t < 2; t++) {
        const u8* qrow = q + ((size_t)(b * N_ + q0 + w * 32 + t * 16 + lr)) * 256;
#pragma unroll
        for (int tq = 0; tq < 4; tq++)
            qf[t][tq] = *(const i64x2*)&qrow[tq * 64 + lq * 16];
    }

    f32x4 oacc[2][16] = {};
    float li[2][4] = {};
    u8* Pw = Ps + w * 1536;

    // Prologue: stage tile 0 into buffer 0.
#pragma unroll
    for (int j = 0; j < 4; j++) {
        gl2lds16(kglob + offK[j], Ks + ((w * 4 + j) << 10));
        gl2lds16(vglob + offV[j], Vt + ((w * 4 + j) << 10));
    }

    for (int mt = 0; mt < 64; mt++) {
        int cur = mt & 1;
        __syncthreads();

        if (mt < 63) {
            const u8* kit = kglob + (size_t)(mt + 1) * 32 * 256;
            const u8* vit = vglob + (mt + 1) * 32;
#pragma unroll
            for (int j = 0; j < 4; j++) {
                gl2lds16(kit + offK[j], Ks + (cur ^ 1) * 8192 + ((w * 4 + j) << 10));
                gl2lds16(vit + offV[j], Vt + (cur ^ 1) * 8192 + ((w * 4 + j) << 10));
            }
        }

        const u8* Kb = Ks + cur * 8192;
        const u8* Vb = Vt + cur * 8192;

        // --- S = Q K^T: 32 queries x 32 keys ---
        f32x4 st[2][2] = {};
#pragma unroll
        for (int kt = 0; kt < 2; kt++) {
            int r = kt * 16 + lr;
#pragma unroll
            for (int tq = 0; tq < 4; tq++) {
                i64x2 kf = *(const i64x2*)&Kb[r * 256 + (((tq * 4 + lq) ^ (r & 15)) << 4)];
                st[0][kt] = mfma_fp8(qf[0][tq].x, kf.x, st[0][kt]);
                st[0][kt] = mfma_fp8(qf[0][tq].y, kf.y, st[0][kt]);
                st[1][kt] = mfma_fp8(qf[1][tq].x, kf.x, st[1][kt]);
                st[1][kt] = mfma_fp8(qf[1][tq].y, kf.y, st[1][kt]);
            }
        }

        // --- fixed-max softmax numerators -> fp8 P (3-op convert, b16 write)
        //     P key order: pos = 2*lr + kt (matches cvt_v's pi permutation) ---
#pragma unroll
        for (int t = 0; t < 2; t++)
#pragma unroll
            for (int r = 0; r < 4; r++) {
                float e0 = __expf(st[t][0][r] * 0.0625f);
                float e1 = __expf(st[t][1][r] * 0.0625f);
                li[t][r] += e0 + e1;
                u16 pk = (u16)((fp8_fast(e0) & 0xff) | ((fp8_fast(e1) & 0xff) << 8));
                *(u16a*)&Pw[(t * 16 + lq * 4 + r) * 48 + lr * 2] = pk;
            }

        // Order the P stores before the P loads (compiler fence + lgkmcnt).
        __threadfence_block();

        // --- PV: P (32x32) x V (32x256) ---
        i64 pf[2];
#pragma unroll
        for (int t = 0; t < 2; t++)
            pf[t] = *(const i64a*)&Pw[(t * 16 + lr) * 48 + lq * 8];
#pragma unroll
        for (int ct = 0; ct < 16; ct++) {
            int row = ct * 16 + lr;
            i64 vf = *(const i64a*)&Vb[row * 32 + (((lq >> 1) ^ ((row >> 2) & 1)) << 4) +
                                       ((lq & 1) << 3)];
            oacc[0][ct] = mfma_fp8(pf[0], vf, oacc[0][ct]);
            oacc[1][ct] = mfma_fp8(pf[1], vf, oacc[1][ct]);
        }
    }

    // Reduce per-lane l partials across the 16 lr-lanes.
    float lsum[2][4];
#pragma unroll
    for (int t = 0; t < 2; t++)
#pragma unroll
        for (int r = 0; r < 4; r++) {
            float s = li[t][r];
            s += __shfl_xor(s, 1);
            s += __shfl_xor(s, 2);
            s += __shfl_xor(s, 4);
            s += __shfl_xor(s, 8);
            lsum[t][r] = s;
        }

    bf16* Op = h ? O1 : O0;
#pragma unroll
    for (int t = 0; t < 2; t++)
#pragma unroll
        for (int ct = 0; ct < 16; ct++)
#pragma unroll
            for (int r = 0; r < 4; r++)
                Op[((size_t)(b * N_ + q0 + w * 32 + t * 16 + lq * 4 + r)) * C_ + ct * 16 + lr] =
                    (bf16)oacc[t][ct][r];
    if (lr == 0) {
        float* lrow = lp + ((size_t)(h * B_ + b)) * N_ + q0 + w * 32;
#pragma unroll
        for (int t = 0; t < 2; t++)
#pragma unroll
            for (int r = 0; r < 4; r++) lrow[t * 16 + lq * 4 + r] = lsum[t][r];
    }
}

// ---------------------------------------------------------------------------
// Kernel 6b: combine the two key-halves: hm = (O0 + O1) / (l0 + l1).
// ---------------------------------------------------------------------------
__global__ __launch_bounds__(256) void combine(bf16* __restrict__ O0,
                                               const bf16* __restrict__ O1,
                                               const float* __restrict__ lp) {
    size_t gid = (size_t)blockIdx.x * 256 + threadIdx.x;  // one per 8 elems
    size_t row = gid >> 5;
    int col = (int)(gid & 31) * 8;
    int b = (int)(row >> 12), n = (int)(row & (N_ - 1));
    float l = lp[(size_t)b * N_ + n] + lp[(size_t)(B_ + b) * N_ + n];
    float inv = 1.f / l;
    bf16x8 a = *(const bf16x8*)&O0[row * C_ + col];
    bf16x8 c = *(const bf16x8*)&O1[row * C_ + col];
    bf16x8 o;
#pragma unroll
    for (int i = 0; i < 8; i++) o[i] = (bf16)(((float)a[i] + (float)c[i]) * inv);
    *(bf16x8*)&O0[row * C_ + col] = o;
}

// ---------------------------------------------------------------------------
// Kernel 7: proj + residual.
// ---------------------------------------------------------------------------
__global__ __launch_bounds__(256) void proj_res(const bf16* __restrict__ W,
                                                const bf16* __restrict__ A,
                                                const float* __restrict__ bias,
                                                const float* __restrict__ x,
                                                float* __restrict__ out) {
    __shared__ __align__(16) bf16 Ws[64][32];
    __shared__ __align__(16) bf16 As[64][32];
    int m0 = blockIdx.x * 64;  // o
    int n0 = blockIdx.y * 64;  // token
    int tid = threadIdx.x;
    int wv = tid >> 6, lane = tid & 63, lr = lane & 15, lq = lane >> 4;
    int wm = (wv & 1) * 32, wn = (wv >> 1) * 32;
    int sr = tid >> 2, sk = (tid & 3) * 8;
    f32x4 acc[2][2] = {};
    for (int kk = 0; kk < C_; kk += 32) {
        __syncthreads();
        *(bf16x8*)&Ws[sr][sk] = *(const bf16x8*)&W[(size_t)(m0 + sr) * C_ + kk + sk];
        *(bf16x8*)&As[sr][sk] = *(const bf16x8*)&A[(size_t)(n0 + sr) * C_ + kk + sk];
        __syncthreads();
        bf16x8 a0 = *(const bf16x8*)&Ws[wm + lr][lq * 8];
        bf16x8 a1 = *(const bf16x8*)&Ws[wm + 16 + lr][lq * 8];
        bf16x8 b0 = *(const bf16x8*)&As[wn + lr][lq * 8];
        bf16x8 b1 = *(const bf16x8*)&As[wn + 16 + lr][lq * 8];
        acc[0][0] = mfma16(a0, b0, acc[0][0]);
        acc[0][1] = mfma16(a0, b1, acc[0][1]);
        acc[1][0] = mfma16(a1, b0, acc[1][0]);
        acc[1][1] = mfma16(a1, b1, acc[1][1]);
    }
    for (int i = 0; i < 2; i++)
        for (int j = 0; j < 2; j++) {
            int T = n0 + wn + j * 16 + lr;
            int b = T >> 12, n = T & (N_ - 1);
            for (int r = 0; r < 4; r++) {
                int o = m0 + wm + i * 16 + lq * 4 + r;
                size_t idx = ((size_t)(b * C_ + o)) * N_ + n;
                out[idx] = x[idx] + acc[i][j][r] + bias[o];
            }
        }
}

// ---------------------------------------------------------------------------
extern "C" void kernel_launch(void* const* d_in, const int* in_sizes, int n_in,
                              void* d_out, int out_size, void* d_ws, size_t ws_size,
                              hipStream_t stream) {
    const float* x = (const float*)d_in[0];
    const float* gsc = (const float*)d_in[1];
    const float* gbi = (const float*)d_in[2];
    const float* wq = (const float*)d_in[3];
    const float* bq = (const float*)d_in[4];
    const float* wk = (const float*)d_in[5];
    const float* bk = (const float*)d_in[6];
    const float* wv = (const float*)d_in[7];
    const float* bv = (const float*)d_in[8];
    const float* wp = (const float*)d_in[9];
    const float* bp = (const float*)d_in[10];
    float* out = (float*)d_out;

    const size_t SZ = (size_t)B_ * N_ * C_;    // 8388608 elements
    const size_t BUF = SZ * 2;                  // bf16 buffer bytes
    char* ws = (char*)d_ws;
    float* gstats = (float*)ws;                 // 4 KB
    bf16* wb = (bf16*)(ws + 4096);              // 512 KB
    char* hnB = ws + 4096 + 524288;             // bf16 hn
    char* qbB = hnB + BUF;                      // bf16 qb
    char* kbB = qbB + BUF;                      // bf16 kb
    char* vTB = kbB + BUF;                      // bf16 vT
    bf16* hn = (bf16*)hnB;
    bf16* qb = (bf16*)qbB;
    bf16* kb = (bf16*)kbB;
    bf16* vT = (bf16*)vTB;
    // reuse of dead regions:
    u8* q8 = (u8*)hnB;            // hn dead after GEMMs
    u8* k8 = (u8*)(hnB + SZ);
    u8* v8 = (u8*)kbB;            // kb dead after cvt_qk (8 MB)
    float* lpart = (float*)(kbB + SZ);  // 256 KB in kb's upper half
    bf16* O0 = (bf16*)qbB;        // qb dead after cvt_qk; becomes hm in-place
    bf16* O1 = (bf16*)vTB;        // vT dead after cvt_v
    bf16* hm = (bf16*)qbB;

    cvt_w<<<256, 256, 0, stream>>>(wq, wk, wv, wp, wb);
    gn_stats<<<B_ * G_, 256, 0, stream>>>(x, gstats);
    gn_apply<<<dim3(N_ / 32, C_ / 32, B_), 256, 0, stream>>>(x, gsc, gbi, gstats, hn);
    gemm_qk<<<dim3(B_ * N_ / 64, C_ / 64), 256, 0, stream>>>(hn, wb, wb + 65536, bq, bk, qb, kb);
    gemm_nt_ch<<<dim3(C_ / 64, B_ * N_ / 64), 256, 0, stream>>>(wb + 131072, hn, bv, vT);
    cvt_qk<<<8192, 256, 0, stream>>>(qb, kb, q8, k8);
    cvt_v<<<8192, 256, 0, stream>>>(vT, v8);
    attn<<<dim3(N_ / 64, 2, B_), 128, 0, stream>>>(q8, k8, v8, O0, O1, lpart);
    combine<<<4096, 256, 0, stream>>>(O0, O1, lpart);
    proj_res<<<dim3(C_ / 64, B_ * N_ / 64), 256, 0, stream>>>(wb + 196608, hm, bp, x, out);
}